// Round 1
// baseline (494.547 us; speedup 1.0000x reference)
//
#include <hip/hip_runtime.h>
#include <hip/hip_bf16.h>

// Problem constants (fixed by setup_inputs)
constexpr int BATCH = 2;
constexpr int CIN   = 16;
constexpr int COUT  = 32;
constexpr int S1    = 32;           // H = W = D = 32
constexpr int HWD   = 32768;        // 32^3
constexpr int OFFC  = 81;           // 3*27 offset channels
constexpr int BIG   = 96;           // 3*32
constexpr int BIG2  = BIG * BIG;    // 9216
constexpr int BIGN  = BIG * BIG * BIG;  // 884736
constexpr int OUTD  = 48;
constexpr int OUT2  = OUTD * OUTD;      // 2304
constexpr int OUTN  = OUTD * OUTD * OUTD; // 110592
constexpr int NOUT  = BATCH * COUT * OUTN; // 7077888

// ---------------------------------------------------------------------------
// K1: offset = conv3d(x, p_w, stride=1, pad=1) + p_b
// thread = (bt, oc-group of 27, pos). w accesses are wave-uniform -> s_load.
__global__ void k_offset_conv(const float* __restrict__ x,
                              const float* __restrict__ p_w,
                              const float* __restrict__ p_b,
                              float* __restrict__ off) {
    int blk   = blockIdx.x;
    int chunk = blk & 127;           // 32768/256 = 128 chunks
    int ocg   = (blk >> 7) % 3;      // 3 groups of 27 oc
    int bt    = blk / 384;
    int pos   = chunk * 256 + threadIdx.x;
    int a = pos >> 10, b = (pos >> 5) & 31, c = pos & 31;

    float acc[27];
#pragma unroll
    for (int m = 0; m < 27; m++) acc[m] = 0.f;

    const float* xb = x + bt * CIN * HWD;
    for (int ci = 0; ci < CIN; ci++) {
        const float* xc = xb + ci * HWD;
        for (int kh = 0; kh < 3; kh++) {
            int ia = a + kh - 1;
            if ((unsigned)ia >= 32u) continue;
            for (int kw = 0; kw < 3; kw++) {
                int ib = b + kw - 1;
                if ((unsigned)ib >= 32u) continue;
                for (int kd = 0; kd < 3; kd++) {
                    int ic = c + kd - 1;
                    if ((unsigned)ic >= 32u) continue;
                    float xv = xc[ia * 1024 + ib * 32 + ic];
                    const float* wp = p_w + (ocg * 27) * 432 + ci * 27 + kh * 9 + kw * 3 + kd;
#pragma unroll
                    for (int m = 0; m < 27; m++) acc[m] += xv * wp[m * 432];
                }
            }
        }
    }
    float* ob = off + (bt * OFFC + ocg * 27) * HWD + pos;
#pragma unroll
    for (int m = 0; m < 27; m++) ob[m * HWD] = acc[m] + p_b[ocg * 27 + m];
}

// ---------------------------------------------------------------------------
// K2: deformable 6-corner sampling -> x_off (2,16,96,96,96)
__global__ void k_interp(const float* __restrict__ x,
                         const float* __restrict__ off,
                         float* __restrict__ xoff) {
    int t  = blockIdx.x * 256 + threadIdx.x;
    int bt = t / BIGN;
    int bp = t - bt * BIGN;
    int A  = bp / BIG2;
    int r  = bp - A * BIG2;
    int Bc = r / BIG;
    int Cc = r - Bc * BIG;
    int a = A / 3,  i = A - a * 3;
    int b = Bc / 3, j = Bc - b * 3;
    int c = Cc / 3, k = Cc - c * 3;
    int n = i * 9 + j * 3 + k;
    int pos = a * 1024 + b * 32 + c;

    const float* ob = off + bt * OFFC * HWD + pos;
    float ox = ob[n * HWD];
    float oy = ob[(27 + n) * HWD];
    float oz = ob[(54 + n) * HWD];

    // reference quirk: px is based on the SECOND coord (b)+j, py on (a)+i
    float px = (float)(b + j) + ox;
    float py = (float)(a + i) + oy;
    float pz = (float)(c + k) + oz;

    float fx = floorf(px), fy = floorf(py), fz = floorf(pz);
    float ltx = fminf(fmaxf(fx, 0.f), 31.f);
    float lty = fminf(fmaxf(fy, 0.f), 31.f);
    float ltz = fminf(fmaxf(fz, 0.f), 31.f);
    float rbx = fminf(fmaxf(fx + 1.f, 0.f), 31.f);
    float rby = fminf(fmaxf(fy + 1.f, 0.f), 31.f);
    float rbz = fminf(fmaxf(fz + 1.f, 0.f), 31.f);
    float pcx = fminf(fmaxf(px, 0.f), 31.f);
    float pcy = fminf(fmaxf(py, 0.f), 31.f);
    float pcz = fminf(fmaxf(pz, 0.f), 31.f);

    float axl = 1.f + (ltx - pcx), axr = 1.f - (rbx - pcx);
    float ayl = 1.f + (lty - pcy), ayr = 1.f - (rby - pcy);
    float azl = 1.f + (ltz - pcz), azr = 1.f - (rbz - pcz);

    float g_lt = axl * ayl * azl;
    float g_rb = axr * ayr * azr;
    float g_lb = axl * ayr * azl;
    float g_rt = axr * ayl * azl;
    float g_lf = axl * ayl * azr;
    float g_rf = axr * ayr * azl;

    int iltx = (int)ltx, ilty = (int)lty, iltz = (int)ltz;
    int irbx = (int)rbx, irby = (int)rby, irbz = (int)rbz;

    int i_lt = iltx * 1024 + ilty * 32 + iltz;
    int i_rb = irbx * 1024 + irby * 32 + irbz;
    int i_lb = iltx * 1024 + irby * 32 + iltz;
    int i_rt = irbx * 1024 + ilty * 32 + iltz;
    int i_lf = iltx * 1024 + ilty * 32 + irbz;
    int i_rf = irbx * 1024 + irby * 32 + iltz;

    const float* xb = x + bt * CIN * HWD;
    float* xo = xoff + (size_t)bt * CIN * BIGN + bp;
#pragma unroll 4
    for (int cc = 0; cc < CIN; cc++) {
        const float* xc = xb + cc * HWD;
        float v = g_lt * xc[i_lt] + g_rb * xc[i_rb] + g_lb * xc[i_lb] +
                  g_rt * xc[i_rt] + g_lf * xc[i_lf] + g_rf * xc[i_rf];
        xo[(size_t)cc * BIGN] = v;
    }
}

// ---------------------------------------------------------------------------
// K3: o = conv3d(x_off, conv_w, stride=2, pad=1); fused partial sum/sumsq
// thread = (bt, pos); 32 accumulators (all co). w uniform -> s_load.
__global__ void k_conv2(const float* __restrict__ xoff,
                        const float* __restrict__ cw,
                        float* __restrict__ out,
                        float* __restrict__ psum,
                        float* __restrict__ psq) {
    int t   = blockIdx.x * 256 + threadIdx.x;
    int bt  = t / OUTN;
    int pos = t - bt * OUTN;
    int u  = pos / OUT2;
    int rr = pos - u * OUT2;
    int v  = rr / OUTD;
    int w  = rr - v * OUTD;

    float acc[32];
#pragma unroll
    for (int m = 0; m < 32; m++) acc[m] = 0.f;

    const float* xb = xoff + (size_t)bt * CIN * BIGN;
    for (int ci = 0; ci < CIN; ci++) {
        const float* xc = xb + (size_t)ci * BIGN;
        for (int k1 = 0; k1 < 3; k1++) {
            int U = 2 * u - 1 + k1;
            if ((unsigned)U >= 96u) continue;
            for (int k2 = 0; k2 < 3; k2++) {
                int V = 2 * v - 1 + k2;
                if ((unsigned)V >= 96u) continue;
                const float* row = xc + U * BIG2 + V * BIG;
                for (int k3 = 0; k3 < 3; k3++) {
                    int Wc = 2 * w - 1 + k3;
                    if ((unsigned)Wc >= 96u) continue;
                    float xv = row[Wc];
                    const float* wp = cw + ci * 27 + k1 * 9 + k2 * 3 + k3;
#pragma unroll
                    for (int m = 0; m < 32; m++) acc[m] += xv * wp[m * 432];
                }
            }
        }
    }

    float* ob = out + (size_t)bt * COUT * OUTN + pos;
#pragma unroll
    for (int m = 0; m < 32; m++) ob[(size_t)m * OUTN] = acc[m];

    // fixed-order (deterministic) block reduction of sum and sum^2 per channel
    int lane = threadIdx.x & 63;
    int wave = threadIdx.x >> 6;
    __shared__ float ls[4][32], lq[4][32];
#pragma unroll
    for (int m = 0; m < 32; m++) {
        float s = acc[m];
        float q = acc[m] * acc[m];
#pragma unroll
        for (int o = 1; o < 64; o <<= 1) {
            s += __shfl_xor(s, o);
            q += __shfl_xor(q, o);
        }
        if (lane == 0) { ls[wave][m] = s; lq[wave][m] = q; }
    }
    __syncthreads();
    if (threadIdx.x < 32) {
        int m = threadIdx.x;
        float s = ls[0][m] + ls[1][m] + ls[2][m] + ls[3][m];
        float q = lq[0][m] + lq[1][m] + lq[2][m] + lq[3][m];
        psum[blockIdx.x * 32 + m] = s;
        psq[blockIdx.x * 32 + m]  = q;
    }
}

// ---------------------------------------------------------------------------
// K4: reduce partials -> per-channel scale A and shift B
__global__ void k_stats(const float* __restrict__ psum,
                        const float* __restrict__ psq,
                        const float* __restrict__ gamma,
                        const float* __restrict__ beta,
                        float* __restrict__ stats) {
    int co  = blockIdx.x;
    int tid = threadIdx.x;
    float s = 0.f, q = 0.f;
    for (int i = tid; i < 864; i += 256) {
        s += psum[i * 32 + co];
        q += psq[i * 32 + co];
    }
    __shared__ float ss[256], sq[256];
    ss[tid] = s; sq[tid] = q;
    __syncthreads();
    for (int st = 128; st > 0; st >>= 1) {
        if (tid < st) { ss[tid] += ss[tid + st]; sq[tid] += sq[tid + st]; }
        __syncthreads();
    }
    if (tid == 0) {
        const float N = 221184.f;  // 2*48^3
        float mean = ss[0] / N;
        float var  = sq[0] / N - mean * mean;
        float inv  = rsqrtf(var + 1e-5f);
        float A = gamma[co] * inv;
        stats[co * 2]     = A;
        stats[co * 2 + 1] = beta[co] - A * mean;
    }
}

// ---------------------------------------------------------------------------
// K5: y = A*o + B; out = y * sigmoid(y)
__global__ void k_bn_silu(float* __restrict__ out,
                          const float* __restrict__ stats) {
    int idx = blockIdx.x * 256 + threadIdx.x;
    int co  = (idx / OUTN) & 31;
    float o = out[idx];
    float y = stats[co * 2] * o + stats[co * 2 + 1];
    out[idx] = y / (1.f + __expf(-y));
}

// ---------------------------------------------------------------------------
extern "C" void kernel_launch(void* const* d_in, const int* in_sizes, int n_in,
                              void* d_out, int out_size, void* d_ws, size_t ws_size,
                              hipStream_t stream) {
    const float* x      = (const float*)d_in[0];
    const float* p_w    = (const float*)d_in[1];
    const float* p_b    = (const float*)d_in[2];
    const float* conv_w = (const float*)d_in[3];
    const float* gamma  = (const float*)d_in[4];
    const float* beta   = (const float*)d_in[5];
    float* out = (float*)d_out;
    float* ws  = (float*)d_ws;

    float* off   = ws;                                 // 2*81*32768   = 5,308,416 f
    float* xoff  = ws + 5308416;                       // 2*16*884736  = 28,311,552 f
    float* psum  = ws + 5308416 + 28311552;            // 864*32
    float* psq   = psum + 27648;                       // 864*32
    float* stats = psq + 27648;                        // 64

    k_offset_conv<<<768, 256, 0, stream>>>(x, p_w, p_b, off);
    k_interp<<<BATCH * BIGN / 256, 256, 0, stream>>>(x, off, xoff);
    k_conv2<<<BATCH * OUTN / 256, 256, 0, stream>>>(xoff, conv_w, out, psum, psq);
    k_stats<<<32, 256, 0, stream>>>(psum, psq, gamma, beta, stats);
    k_bn_silu<<<NOUT / 256, 256, 0, stream>>>(out, stats);
}

// Round 2
// 333.872 us; speedup vs baseline: 1.4812x; 1.4812x over previous
//
#include <hip/hip_runtime.h>
#include <hip/hip_bf16.h>

// Problem constants (fixed by setup_inputs)
constexpr int BATCH = 2;
constexpr int CIN   = 16;
constexpr int COUT  = 32;
constexpr int HWD   = 32768;        // 32^3
constexpr int OFFC  = 81;           // 3*27 offset channels
constexpr int BIG   = 96;           // 3*32
constexpr int BIG2  = BIG * BIG;    // 9216
constexpr int BIGN  = BIG * BIG * BIG;  // 884736
constexpr int OUTD  = 48;
constexpr int OUT2  = OUTD * OUTD;      // 2304
constexpr int OUTN  = OUTD * OUTD * OUTD; // 110592
constexpr int NOUT  = BATCH * COUT * OUTN; // 7077888

// ---------------------------------------------------------------------------
// K0a: weight transposes. wT[(ci*27+tap)*32+co] = conv_w[co][ci][tap]
//      pwT[(ci*27+tap)*81+oc] = p_w[oc][ci][tap]
__global__ __launch_bounds__(256) void k_wtrans(const float* __restrict__ cw,
                                                const float* __restrict__ pw,
                                                float* __restrict__ wT,
                                                float* __restrict__ pwT) {
    int t = blockIdx.x * 256 + threadIdx.x;
    if (t < 13824) {
        int co = t & 31, kt = t >> 5;           // kt = ci*27+tap in [0,432)
        wT[t] = cw[co * 432 + kt];
    } else if (t < 13824 + 34992) {
        int u = t - 13824;
        int oc = u % 81, kt = u / 81;
        pwT[kt * 81 + oc] = pw[oc * 432 + kt];
    }
}

// ---------------------------------------------------------------------------
// K0b: transpose x (b,ci,pos) -> xt (b,pos,ci) so channel gathers are float4
__global__ __launch_bounds__(256) void k_xt(const float* __restrict__ x,
                                            float* __restrict__ xt) {
    int t = blockIdx.x * 256 + threadIdx.x;   // 65536 threads
    int bt = t >> 15, pos = t & 32767;
    float v[16];
#pragma unroll
    for (int ci = 0; ci < 16; ci++) v[ci] = x[(bt * 16 + ci) * HWD + pos];
    float4* dst = (float4*)(xt + (size_t)t * 16);
    dst[0] = make_float4(v[0], v[1], v[2], v[3]);
    dst[1] = make_float4(v[4], v[5], v[6], v[7]);
    dst[2] = make_float4(v[8], v[9], v[10], v[11]);
    dst[3] = make_float4(v[12], v[13], v[14], v[15]);
}

// ---------------------------------------------------------------------------
// K1: offset conv (stride 1, pad 1), LDS-tiled. Block = 4x8x8 output tile,
// one of 3 oc-groups of 27. Grid = bt(2) x ocg(3) x 128 tiles = 768.
__global__ __launch_bounds__(256) void k_offset_conv(const float* __restrict__ x,
                                                     const float* __restrict__ pwT,
                                                     const float* __restrict__ p_b,
                                                     float* __restrict__ off) {
    __shared__ float lt[2][6 * 10 * 11];      // 660 floats per buffer
    int blk  = blockIdx.x;
    int tile = blk & 127;
    int ocg  = (blk >> 7) % 3;
    int bt   = blk / 384;
    int a0 = (tile >> 4) * 4, b0 = ((tile >> 2) & 3) * 8, c0 = (tile & 3) * 8;
    int tid = threadIdx.x;
    int tu = tid >> 6, tv = (tid >> 3) & 7, tw = tid & 7;

    const float* xb = x + (size_t)bt * CIN * HWD;

    auto stage = [&](int ci, int bf) {
        const float* xc = xb + (size_t)ci * HWD;
        float* L = lt[bf];
        for (int s = tid; s < 600; s += 256) {
            int su = s / 100; int rem = s - su * 100;
            int sv = rem / 10; int sw = rem - sv * 10;
            int ia = a0 - 1 + su, ib = b0 - 1 + sv, ic = c0 - 1 + sw;
            float val = 0.f;
            if ((unsigned)ia < 32u && (unsigned)ib < 32u && (unsigned)ic < 32u)
                val = xc[ia * 1024 + ib * 32 + ic];
            L[su * 110 + sv * 11 + sw] = val;
        }
    };

    float acc[27];
#pragma unroll
    for (int m = 0; m < 27; m++) acc[m] = 0.f;

    stage(0, 0);
#pragma unroll 1
    for (int ci = 0; ci < 16; ci++) {
        __syncthreads();
        if (ci + 1 < 16) stage(ci + 1, (ci + 1) & 1);
        const float* L = lt[ci & 1] + tu * 110 + tv * 11 + tw;
        const float* wp = pwT + ci * 27 * 81 + ocg * 27;
#pragma unroll
        for (int kh = 0; kh < 3; kh++)
#pragma unroll
        for (int kw = 0; kw < 3; kw++)
#pragma unroll
        for (int kd = 0; kd < 3; kd++) {
            float xv = L[kh * 110 + kw * 11 + kd];
            const float* w = wp + (kh * 9 + kw * 3 + kd) * 81;
#pragma unroll
            for (int m = 0; m < 27; m++) acc[m] += xv * w[m];
        }
    }

    int a = a0 + tu, b = b0 + tv, c = c0 + tw;
    int pos = a * 1024 + b * 32 + c;
    float* ob = off + ((size_t)bt * OFFC + ocg * 27) * HWD + pos;
#pragma unroll
    for (int m = 0; m < 27; m++) ob[(size_t)m * HWD] = acc[m] + p_b[ocg * 27 + m];
}

// ---------------------------------------------------------------------------
// K2: deformable 6-corner sampling -> x_off bf16 (2,16,96,96,96), gathers via xt
__global__ __launch_bounds__(256) void k_interp(const float* __restrict__ xt,
                                                const float* __restrict__ off,
                                                __hip_bfloat16* __restrict__ xoffb) {
    int t  = blockIdx.x * 256 + threadIdx.x;
    int bt = t / BIGN;
    int bp = t - bt * BIGN;
    int A  = bp / BIG2;
    int r  = bp - A * BIG2;
    int Bc = r / BIG;
    int Cc = r - Bc * BIG;
    int a = A / 3,  i = A - a * 3;
    int b = Bc / 3, j = Bc - b * 3;
    int c = Cc / 3, k = Cc - c * 3;
    int n = i * 9 + j * 3 + k;
    int pos = a * 1024 + b * 32 + c;

    const float* ob = off + (size_t)bt * OFFC * HWD + pos;
    float ox = ob[(size_t)n * HWD];
    float oy = ob[(size_t)(27 + n) * HWD];
    float oz = ob[(size_t)(54 + n) * HWD];

    // reference quirk: px is based on the SECOND coord (b)+j, py on (a)+i
    float px = (float)(b + j) + ox;
    float py = (float)(a + i) + oy;
    float pz = (float)(c + k) + oz;

    float fx = floorf(px), fy = floorf(py), fz = floorf(pz);
    float ltx = fminf(fmaxf(fx, 0.f), 31.f);
    float lty = fminf(fmaxf(fy, 0.f), 31.f);
    float ltz = fminf(fmaxf(fz, 0.f), 31.f);
    float rbx = fminf(fmaxf(fx + 1.f, 0.f), 31.f);
    float rby = fminf(fmaxf(fy + 1.f, 0.f), 31.f);
    float rbz = fminf(fmaxf(fz + 1.f, 0.f), 31.f);
    float pcx = fminf(fmaxf(px, 0.f), 31.f);
    float pcy = fminf(fmaxf(py, 0.f), 31.f);
    float pcz = fminf(fmaxf(pz, 0.f), 31.f);

    float axl = 1.f + (ltx - pcx), axr = 1.f - (rbx - pcx);
    float ayl = 1.f + (lty - pcy), ayr = 1.f - (rby - pcy);
    float azl = 1.f + (ltz - pcz), azr = 1.f - (rbz - pcz);

    float g_lt = axl * ayl * azl;
    float g_rb = axr * ayr * azr;
    float g_lb = axl * ayr * azl;
    float g_rt = axr * ayl * azl;
    float g_lf = axl * ayl * azr;
    float g_rf = axr * ayr * azl;

    int iltx = (int)ltx, ilty = (int)lty, iltz = (int)ltz;
    int irbx = (int)rbx, irby = (int)rby, irbz = (int)rbz;

    int i_lt = iltx * 1024 + ilty * 32 + iltz;
    int i_rb = irbx * 1024 + irby * 32 + irbz;
    int i_lb = iltx * 1024 + irby * 32 + iltz;
    int i_rt = irbx * 1024 + ilty * 32 + iltz;
    int i_lf = iltx * 1024 + ilty * 32 + irbz;
    int i_rf = irbx * 1024 + irby * 32 + iltz;

    const float4* xb4 = (const float4*)(xt + (size_t)bt * HWD * 16);
    float4 a0 = make_float4(0.f, 0.f, 0.f, 0.f), a1 = a0, a2 = a0, a3 = a0;

    auto corner = [&](float g, int ip) {
        const float4* p = xb4 + (size_t)ip * 4;
        float4 v0 = p[0], v1 = p[1], v2 = p[2], v3 = p[3];
        a0.x += g * v0.x; a0.y += g * v0.y; a0.z += g * v0.z; a0.w += g * v0.w;
        a1.x += g * v1.x; a1.y += g * v1.y; a1.z += g * v1.z; a1.w += g * v1.w;
        a2.x += g * v2.x; a2.y += g * v2.y; a2.z += g * v2.z; a2.w += g * v2.w;
        a3.x += g * v3.x; a3.y += g * v3.y; a3.z += g * v3.z; a3.w += g * v3.w;
    };
    corner(g_lt, i_lt);
    corner(g_rb, i_rb);
    corner(g_lb, i_lb);
    corner(g_rt, i_rt);
    corner(g_lf, i_lf);
    corner(g_rf, i_rf);

    float vals[16] = {a0.x, a0.y, a0.z, a0.w, a1.x, a1.y, a1.z, a1.w,
                      a2.x, a2.y, a2.z, a2.w, a3.x, a3.y, a3.z, a3.w};
    __hip_bfloat16* xo = xoffb + (size_t)bt * CIN * BIGN + bp;
#pragma unroll
    for (int cc = 0; cc < 16; cc++)
        xo[(size_t)cc * BIGN] = __float2bfloat16(vals[cc]);
}

// ---------------------------------------------------------------------------
// K3: conv3d(x_off, conv_w, stride=2, pad=1), LDS-tiled, bf16 input.
// Block = 4x8x8 output tile (u,v,w), all 32 co. Grid = 2 x 12 x 6 x 6 = 864.
// LDS region per ci: U 9 x V 17 x W 17, W stored even/odd-split (stride-1 reads).
__global__ __launch_bounds__(256) void k_conv2(const __hip_bfloat16* __restrict__ xoffb,
                                               const float* __restrict__ wT,
                                               float* __restrict__ out,
                                               float* __restrict__ psum,
                                               float* __restrict__ psq) {
    __shared__ float lt[2][9 * 17 * 18];     // 2754 floats per buffer
    int blk = blockIdx.x;
    int bt = blk / 432; int r = blk - bt * 432;
    int ut = r / 36; r -= ut * 36;
    int vt = r / 6;  int wt = r - vt * 6;
    int u0 = ut * 4, v0 = vt * 8, w0 = wt * 8;
    int tid = threadIdx.x;
    int tu = tid >> 6, tv = (tid >> 3) & 7, tw = tid & 7;

    const ushort* xbase = (const ushort*)xoffb + (size_t)bt * CIN * BIGN;

    auto stage = [&](int ci, int bf) {
        const ushort* xc = xbase + (size_t)ci * BIGN;
        float* L = lt[bf];
        for (int s = tid; s < 9 * 17 * 17; s += 256) {
            int su = s / 289; int rem = s - su * 289;
            int sv = rem / 17; int sw = rem - sv * 17;
            int U = 2 * u0 - 1 + su, V = 2 * v0 - 1 + sv, W = 2 * w0 - 1 + sw;
            float val = 0.f;
            if ((unsigned)U < 96u && (unsigned)V < 96u && (unsigned)W < 96u)
                val = __uint_as_float(((unsigned)xc[U * 9216 + V * 96 + W]) << 16);
            // even/odd split along W: even half at [0..8], odd half at [9..16]
            L[su * 306 + sv * 18 + (sw & 1) * 9 + (sw >> 1)] = val;
        }
    };

    float acc[32];
#pragma unroll
    for (int m = 0; m < 32; m++) acc[m] = 0.f;

    stage(0, 0);
#pragma unroll 1
    for (int ci = 0; ci < 16; ci++) {
        __syncthreads();
        if (ci + 1 < 16) stage(ci + 1, (ci + 1) & 1);
        // thread reads at (2tu+k1, 2tv+k2, 2tw+k3); W offset map k3 -> {0, 9, 1}
        const float* L = lt[ci & 1] + (2 * tu) * 306 + (2 * tv) * 18 + tw;
        const float* wp = wT + ci * 27 * 32;
#pragma unroll
        for (int k1 = 0; k1 < 3; k1++)
#pragma unroll
        for (int k2 = 0; k2 < 3; k2++)
#pragma unroll
        for (int k3 = 0; k3 < 3; k3++) {
            const int woff = (k3 == 0) ? 0 : (k3 == 1 ? 9 : 1);
            float xv = L[k1 * 306 + k2 * 18 + woff];
            const float* w = wp + (k1 * 9 + k2 * 3 + k3) * 32;
#pragma unroll
            for (int m = 0; m < 32; m++) acc[m] += xv * w[m];
        }
    }

    int u = u0 + tu, v = v0 + tv, w = w0 + tw;
    int pos = u * OUT2 + v * OUTD + w;
    float* ob = out + (size_t)bt * COUT * OUTN + pos;
#pragma unroll
    for (int m = 0; m < 32; m++) ob[(size_t)m * OUTN] = acc[m];

    // fixed-order (deterministic) block reduction of sum and sum^2 per channel
    int lane = tid & 63;
    int wave = tid >> 6;
    __shared__ float ls[4][32], lq[4][32];
#pragma unroll
    for (int m = 0; m < 32; m++) {
        float s = acc[m];
        float q = acc[m] * acc[m];
#pragma unroll
        for (int o = 1; o < 64; o <<= 1) {
            s += __shfl_xor(s, o);
            q += __shfl_xor(q, o);
        }
        if (lane == 0) { ls[wave][m] = s; lq[wave][m] = q; }
    }
    __syncthreads();
    if (tid < 32) {
        int m = tid;
        float s = ls[0][m] + ls[1][m] + ls[2][m] + ls[3][m];
        float q = lq[0][m] + lq[1][m] + lq[2][m] + lq[3][m];
        psum[blockIdx.x * 32 + m] = s;
        psq[blockIdx.x * 32 + m]  = q;
    }
}

// ---------------------------------------------------------------------------
// K4: reduce partials -> per-channel scale A and shift B
__global__ __launch_bounds__(256) void k_stats(const float* __restrict__ psum,
                                               const float* __restrict__ psq,
                                               const float* __restrict__ gamma,
                                               const float* __restrict__ beta,
                                               float* __restrict__ stats) {
    int co  = blockIdx.x;
    int tid = threadIdx.x;
    float s = 0.f, q = 0.f;
    for (int i = tid; i < 864; i += 256) {
        s += psum[i * 32 + co];
        q += psq[i * 32 + co];
    }
    __shared__ float ss[256], sq[256];
    ss[tid] = s; sq[tid] = q;
    __syncthreads();
    for (int st = 128; st > 0; st >>= 1) {
        if (tid < st) { ss[tid] += ss[tid + st]; sq[tid] += sq[tid + st]; }
        __syncthreads();
    }
    if (tid == 0) {
        const float N = 221184.f;  // 2*48^3
        float mean = ss[0] / N;
        float var  = sq[0] / N - mean * mean;
        float inv  = rsqrtf(var + 1e-5f);
        float A = gamma[co] * inv;
        stats[co * 2]     = A;
        stats[co * 2 + 1] = beta[co] - A * mean;
    }
}

// ---------------------------------------------------------------------------
// K5: y = A*o + B; out = y * sigmoid(y)   (float4 vectorized)
__global__ __launch_bounds__(256) void k_bn_silu(float* __restrict__ out,
                                                 const float* __restrict__ stats) {
    int idx4 = blockIdx.x * 256 + threadIdx.x;
    int co = (idx4 / (OUTN / 4)) & 31;
    float A = stats[co * 2], B = stats[co * 2 + 1];
    float4 o = ((const float4*)out)[idx4];
    float4 y;
    y.x = A * o.x + B; y.y = A * o.y + B; y.z = A * o.z + B; y.w = A * o.w + B;
    y.x = y.x / (1.f + __expf(-y.x));
    y.y = y.y / (1.f + __expf(-y.y));
    y.z = y.z / (1.f + __expf(-y.z));
    y.w = y.w / (1.f + __expf(-y.w));
    ((float4*)out)[idx4] = y;
}

// ---------------------------------------------------------------------------
extern "C" void kernel_launch(void* const* d_in, const int* in_sizes, int n_in,
                              void* d_out, int out_size, void* d_ws, size_t ws_size,
                              hipStream_t stream) {
    const float* x      = (const float*)d_in[0];
    const float* p_w    = (const float*)d_in[1];
    const float* p_b    = (const float*)d_in[2];
    const float* conv_w = (const float*)d_in[3];
    const float* gamma  = (const float*)d_in[4];
    const float* beta   = (const float*)d_in[5];
    float* out = (float*)d_out;
    float* ws  = (float*)d_ws;

    float* off   = ws;                       // 5,308,416 f
    float* xt    = off + 5308416;            // 1,048,576 f
    float* wT    = xt + 1048576;             // 13,824 f
    float* pwT   = wT + 13824;               // 34,992 f
    float* psum  = pwT + 34992;              // 27,648 f
    float* psq   = psum + 27648;             // 27,648 f
    float* stats = psq + 27648;              // 64 f
    __hip_bfloat16* xoffb = (__hip_bfloat16*)(stats + 64);  // 28,311,552 bf16

    k_wtrans<<<191, 256, 0, stream>>>(conv_w, p_w, wT, pwT);
    k_xt<<<256, 256, 0, stream>>>(x, xt);
    k_offset_conv<<<768, 256, 0, stream>>>(x, pwT, p_b, off);
    k_interp<<<BATCH * BIGN / 256, 256, 0, stream>>>(xt, off, xoffb);
    k_conv2<<<864, 256, 0, stream>>>(xoffb, wT, out, psum, psq);
    k_stats<<<32, 256, 0, stream>>>(psum, psq, gamma, beta, stats);
    k_bn_silu<<<NOUT / 1024, 256, 0, stream>>>(out, stats);
}

// Round 3
// 215.372 us; speedup vs baseline: 2.2963x; 1.5502x over previous
//
#include <hip/hip_runtime.h>
#include <hip/hip_bf16.h>

// Problem constants (fixed by setup_inputs)
constexpr int BATCH = 2;
constexpr int CIN   = 16;
constexpr int COUT  = 32;
constexpr int HWD   = 32768;        // 32^3
constexpr int OFFC  = 81;           // 3*27 offset channels
constexpr int BIG   = 96;           // 3*32
constexpr int BIG2  = BIG * BIG;    // 9216
constexpr int BIGN  = BIG * BIG * BIG;  // 884736
constexpr int OUTD  = 48;
constexpr int OUT2  = OUTD * OUTD;      // 2304
constexpr int OUTN  = OUTD * OUTD * OUTD; // 110592
constexpr int NOUT  = BATCH * COUT * OUTN; // 7077888
constexpr int NBLK3 = 1728;         // K3 grid: 2 bt x 24 ut x 6 vt x 6 wt

typedef __attribute__((ext_vector_type(8)))  short bf16x8;
typedef __attribute__((ext_vector_type(16))) float f32x16;

// ---------------------------------------------------------------------------
// K0a: weight transposes.
//  wTb[(tap*32+co)*16+ci] = bf16(conv_w[co][ci][tap])   (MFMA A/B-friendly)
//  pwT[(ci*27+tap)*81+oc] = p_w[oc][ci][tap]            (K1, fp32)
__global__ __launch_bounds__(256) void k_wtrans(const float* __restrict__ cw,
                                                const float* __restrict__ pw,
                                                ushort* __restrict__ wTb,
                                                float* __restrict__ pwT) {
    int t = blockIdx.x * 256 + threadIdx.x;
    if (t < 13824) {
        int ci = t & 15; int rr = t >> 4; int co = rr & 31; int tap = rr >> 5;
        float v = cw[co * 432 + ci * 27 + tap];
        __hip_bfloat16 h = __float2bfloat16(v);
        wTb[t] = *(ushort*)&h;
    } else if (t < 13824 + 34992) {
        int u = t - 13824;
        int oc = u % 81, kt = u / 81;
        pwT[kt * 81 + oc] = pw[oc * 432 + kt];
    }
}

// ---------------------------------------------------------------------------
// K0b: transpose x (b,ci,pos) -> xt (b,pos,ci) so channel gathers are float4
__global__ __launch_bounds__(256) void k_xt(const float* __restrict__ x,
                                            float* __restrict__ xt) {
    int t = blockIdx.x * 256 + threadIdx.x;   // 65536 threads
    int bt = t >> 15, pos = t & 32767;
    float v[16];
#pragma unroll
    for (int ci = 0; ci < 16; ci++) v[ci] = x[(bt * 16 + ci) * HWD + pos];
    float4* dst = (float4*)(xt + (size_t)t * 16);
    dst[0] = make_float4(v[0], v[1], v[2], v[3]);
    dst[1] = make_float4(v[4], v[5], v[6], v[7]);
    dst[2] = make_float4(v[8], v[9], v[10], v[11]);
    dst[3] = make_float4(v[12], v[13], v[14], v[15]);
}

// ---------------------------------------------------------------------------
// K1: offset conv (stride 1, pad 1), LDS-tiled fmac. Block = 4x8x8 output
// tile, one of 3 oc-groups of 27. Grid = bt(2) x ocg(3) x 128 tiles = 768.
__global__ __launch_bounds__(256) void k_offset_conv(const float* __restrict__ x,
                                                     const float* __restrict__ pwT,
                                                     const float* __restrict__ p_b,
                                                     float* __restrict__ off) {
    __shared__ float lt[2][6 * 10 * 11];
    int blk  = blockIdx.x;
    int tile = blk & 127;
    int ocg  = (blk >> 7) % 3;
    int bt   = blk / 384;
    int a0 = (tile >> 4) * 4, b0 = ((tile >> 2) & 3) * 8, c0 = (tile & 3) * 8;
    int tid = threadIdx.x;
    int tu = tid >> 6, tv = (tid >> 3) & 7, tw = tid & 7;

    const float* xb = x + (size_t)bt * CIN * HWD;

    auto stage = [&](int ci, int bf) {
        const float* xc = xb + (size_t)ci * HWD;
        float* L = lt[bf];
        for (int s = tid; s < 600; s += 256) {
            int su = s / 100; int rem = s - su * 100;
            int sv = rem / 10; int sw = rem - sv * 10;
            int ia = a0 - 1 + su, ib = b0 - 1 + sv, ic = c0 - 1 + sw;
            float val = 0.f;
            if ((unsigned)ia < 32u && (unsigned)ib < 32u && (unsigned)ic < 32u)
                val = xc[ia * 1024 + ib * 32 + ic];
            L[su * 110 + sv * 11 + sw] = val;
        }
    };

    float acc[27];
#pragma unroll
    for (int m = 0; m < 27; m++) acc[m] = 0.f;

    stage(0, 0);
#pragma unroll 1
    for (int ci = 0; ci < 16; ci++) {
        __syncthreads();
        if (ci + 1 < 16) stage(ci + 1, (ci + 1) & 1);
        const float* L = lt[ci & 1] + tu * 110 + tv * 11 + tw;
        const float* wp = pwT + ci * 27 * 81 + ocg * 27;
#pragma unroll
        for (int kh = 0; kh < 3; kh++)
#pragma unroll
        for (int kw = 0; kw < 3; kw++)
#pragma unroll
        for (int kd = 0; kd < 3; kd++) {
            float xv = L[kh * 110 + kw * 11 + kd];
            const float* w = wp + (kh * 9 + kw * 3 + kd) * 81;
#pragma unroll
            for (int m = 0; m < 27; m++) acc[m] += xv * w[m];
        }
    }

    int a = a0 + tu, b = b0 + tv, c = c0 + tw;
    int pos = a * 1024 + b * 32 + c;
    float* ob = off + ((size_t)bt * OFFC + ocg * 27) * HWD + pos;
#pragma unroll
    for (int m = 0; m < 27; m++) ob[(size_t)m * HWD] = acc[m] + p_b[ocg * 27 + m];
}

// ---------------------------------------------------------------------------
// K2: deformable 6-corner sampling -> x_off bf16 CHANNEL-LAST (bt, pos, 16ci)
__global__ __launch_bounds__(256) void k_interp(const float* __restrict__ xt,
                                                const float* __restrict__ off,
                                                ushort* __restrict__ xoffb) {
    int t  = blockIdx.x * 256 + threadIdx.x;
    int bt = t / BIGN;
    int bp = t - bt * BIGN;
    int A  = bp / BIG2;
    int r  = bp - A * BIG2;
    int Bc = r / BIG;
    int Cc = r - Bc * BIG;
    int a = A / 3,  i = A - a * 3;
    int b = Bc / 3, j = Bc - b * 3;
    int c = Cc / 3, k = Cc - c * 3;
    int n = i * 9 + j * 3 + k;
    int pos = a * 1024 + b * 32 + c;

    const float* ob = off + (size_t)bt * OFFC * HWD + pos;
    float ox = ob[(size_t)n * HWD];
    float oy = ob[(size_t)(27 + n) * HWD];
    float oz = ob[(size_t)(54 + n) * HWD];

    // reference quirk: px is based on the SECOND coord (b)+j, py on (a)+i
    float px = (float)(b + j) + ox;
    float py = (float)(a + i) + oy;
    float pz = (float)(c + k) + oz;

    float fx = floorf(px), fy = floorf(py), fz = floorf(pz);
    float ltx = fminf(fmaxf(fx, 0.f), 31.f);
    float lty = fminf(fmaxf(fy, 0.f), 31.f);
    float ltz = fminf(fmaxf(fz, 0.f), 31.f);
    float rbx = fminf(fmaxf(fx + 1.f, 0.f), 31.f);
    float rby = fminf(fmaxf(fy + 1.f, 0.f), 31.f);
    float rbz = fminf(fmaxf(fz + 1.f, 0.f), 31.f);
    float pcx = fminf(fmaxf(px, 0.f), 31.f);
    float pcy = fminf(fmaxf(py, 0.f), 31.f);
    float pcz = fminf(fmaxf(pz, 0.f), 31.f);

    float axl = 1.f + (ltx - pcx), axr = 1.f - (rbx - pcx);
    float ayl = 1.f + (lty - pcy), ayr = 1.f - (rby - pcy);
    float azl = 1.f + (ltz - pcz), azr = 1.f - (rbz - pcz);

    float g_lt = axl * ayl * azl;
    float g_rb = axr * ayr * azr;
    float g_lb = axl * ayr * azl;
    float g_rt = axr * ayl * azl;
    float g_lf = axl * ayl * azr;
    float g_rf = axr * ayr * azl;

    int iltx = (int)ltx, ilty = (int)lty, iltz = (int)ltz;
    int irbx = (int)rbx, irby = (int)rby, irbz = (int)rbz;

    int i_lt = iltx * 1024 + ilty * 32 + iltz;
    int i_rb = irbx * 1024 + irby * 32 + irbz;
    int i_lb = iltx * 1024 + irby * 32 + iltz;
    int i_rt = irbx * 1024 + ilty * 32 + iltz;
    int i_lf = iltx * 1024 + ilty * 32 + irbz;
    int i_rf = irbx * 1024 + irby * 32 + iltz;

    const float4* xb4 = (const float4*)(xt + (size_t)bt * HWD * 16);
    float4 a0 = make_float4(0.f, 0.f, 0.f, 0.f), a1 = a0, a2 = a0, a3 = a0;

    auto corner = [&](float g, int ip) {
        const float4* p = xb4 + (size_t)ip * 4;
        float4 v0 = p[0], v1 = p[1], v2 = p[2], v3 = p[3];
        a0.x += g * v0.x; a0.y += g * v0.y; a0.z += g * v0.z; a0.w += g * v0.w;
        a1.x += g * v1.x; a1.y += g * v1.y; a1.z += g * v1.z; a1.w += g * v1.w;
        a2.x += g * v2.x; a2.y += g * v2.y; a2.z += g * v2.z; a2.w += g * v2.w;
        a3.x += g * v3.x; a3.y += g * v3.y; a3.z += g * v3.z; a3.w += g * v3.w;
    };
    corner(g_lt, i_lt);
    corner(g_rb, i_rb);
    corner(g_lb, i_lb);
    corner(g_rt, i_rt);
    corner(g_lf, i_lf);
    corner(g_rf, i_rf);

    float vals[16] = {a0.x, a0.y, a0.z, a0.w, a1.x, a1.y, a1.z, a1.w,
                      a2.x, a2.y, a2.z, a2.w, a3.x, a3.y, a3.z, a3.w};
    uint uw[8];
#pragma unroll
    for (int cc = 0; cc < 8; cc++) {
        __hip_bfloat16 h0 = __float2bfloat16(vals[2 * cc]);
        __hip_bfloat16 h1 = __float2bfloat16(vals[2 * cc + 1]);
        uw[cc] = (uint)(*(ushort*)&h0) | ((uint)(*(ushort*)&h1) << 16);
    }
    uint4* dst = (uint4*)(xoffb + (size_t)(bt * (size_t)BIGN + bp) * 16);
    dst[0] = make_uint4(uw[0], uw[1], uw[2], uw[3]);
    dst[1] = make_uint4(uw[4], uw[5], uw[6], uw[7]);
}

// ---------------------------------------------------------------------------
// K3: conv3d(x_off, conv_w, stride=2, pad=1) as implicit-GEMM MFMA.
// Block = 2x8x8 output tile, 4 waves; wave = one 32-position x 32-co MFMA tile.
// 27 taps x mfma_f32_32x32x16_bf16 (K=16 ci). A = weights [co][ci] (row=co),
// B = x [ci][pos] (col=pos)  ->  D[co][pos], position-major stores.
// LDS halo: [su 0..4][sv 0..16][W-slot even/odd split, pad 19][16 ci] bf16.
__global__ __launch_bounds__(256, 3) void k_conv2(const ushort* __restrict__ xoffb,
                                                  const ushort* __restrict__ wTb,
                                                  float* __restrict__ out,
                                                  float* __restrict__ psum,
                                                  float* __restrict__ psq) {
    __shared__ uint4 lds[5 * 17 * 19 * 2];   // 51,680 B
    __shared__ float ls[4][32], lq[4][32];

    int blk = blockIdx.x;
    int bt = blk / 864; int r = blk - bt * 864;
    int ut = r / 36; r -= ut * 36;
    int vt = r / 6;  int wt = r - vt * 6;

    int tid = threadIdx.x;
    int wv = tid >> 6, l = tid & 63;
    int col = l & 31, half = l >> 5;

    // preload all 27 weight fragments (A operand): w[co=col][ci=half*8..+7]
    bf16x8 wf[27];
    const uint4* wt4 = (const uint4*)wTb;
#pragma unroll
    for (int t = 0; t < 27; t++)
        wf[t] = __builtin_bit_cast(bf16x8, wt4[(t * 32 + col) * 2 + half]);

    // stage halo (5 x 17 x 17 points x 16ci bf16), even/odd W split, row pad 19
    const ushort* xb = xoffb + (size_t)bt * BIGN * 16;
    int gU0 = ut * 4 - 1, gV0 = vt * 16 - 1, gW0 = wt * 16 - 1;
    for (int s = tid; s < 2890; s += 256) {
        int h = s & 1, p = s >> 1;
        int su = p / 289; int rm = p - su * 289;
        int sv = rm / 17; int sw = rm - sv * 17;
        int gU = gU0 + su, gV = gV0 + sv, gW = gW0 + sw;
        uint4 v = make_uint4(0, 0, 0, 0);
        if ((unsigned)gU < 96u && (unsigned)gV < 96u && (unsigned)gW < 96u)
            v = *(const uint4*)(xb + (size_t)(gU * 9216 + gV * 96 + gW) * 16 + h * 8);
        int slot = (sw & 1) * 9 + (sw >> 1);
        lds[((su * 17 + sv) * 19 + slot) * 2 + h] = v;
    }
    __syncthreads();

    // wave tile: U = wv>>1 in {0,1}; V = (wv&1)*4 + col>>3; W = col&7
    int U = wv >> 1, V = (wv & 1) * 4 + (col >> 3), W = col & 7;
    const uint4* lp = &lds[(((2 * U * 17 + 2 * V) * 19) + W) * 2 + half];

    f32x16 acc;
#pragma unroll
    for (int i = 0; i < 16; i++) acc[i] = 0.f;

#pragma unroll
    for (int k1 = 0; k1 < 3; k1++)
#pragma unroll
    for (int k2 = 0; k2 < 3; k2++)
#pragma unroll
    for (int k3 = 0; k3 < 3; k3++) {
        // sw = 2W + k3 -> slot offset {0, 9, 1}
        const int so = (k3 == 0) ? 0 : (k3 == 1 ? 9 : 1);
        const int off = ((k1 * 17 + k2) * 19 + so) * 2;
        bf16x8 xf = __builtin_bit_cast(bf16x8, lp[off]);
        acc = __builtin_amdgcn_mfma_f32_32x32x16_bf16(wf[(k1 * 3 + k2) * 3 + k3],
                                                      xf, acc, 0, 0, 0);
    }

    // store: D row = co = (rg&3)+8*(rg>>2)+4*half, col = position
    int u = ut * 2 + U, v = vt * 8 + V, wg = wt * 8 + W;
    size_t posg = (size_t)u * OUT2 + v * OUTD + wg;
    float* ob = out + (size_t)bt * COUT * OUTN;
#pragma unroll
    for (int rg = 0; rg < 16; rg++) {
        int co = (rg & 3) + 8 * (rg >> 2) + 4 * half;
        ob[(size_t)co * OUTN + posg] = acc[rg];
    }

    // fixed-order block stats (sum over the 32 positions per half-wave)
#pragma unroll
    for (int rg = 0; rg < 16; rg++) {
        float s = acc[rg], q = acc[rg] * acc[rg];
#pragma unroll
        for (int o = 1; o < 32; o <<= 1) {
            s += __shfl_xor(s, o);
            q += __shfl_xor(q, o);
        }
        if (col == 0) {
            int co = (rg & 3) + 8 * (rg >> 2) + 4 * half;
            ls[wv][co] = s; lq[wv][co] = q;
        }
    }
    __syncthreads();
    if (tid < 32) {
        float s = ls[0][tid] + ls[1][tid] + ls[2][tid] + ls[3][tid];
        float q = lq[0][tid] + lq[1][tid] + lq[2][tid] + lq[3][tid];
        psum[blk * 32 + tid] = s;
        psq[blk * 32 + tid]  = q;
    }
}

// ---------------------------------------------------------------------------
// K4: reduce partials -> per-channel scale A and shift B
__global__ __launch_bounds__(256) void k_stats(const float* __restrict__ psum,
                                               const float* __restrict__ psq,
                                               const float* __restrict__ gamma,
                                               const float* __restrict__ beta,
                                               float* __restrict__ stats) {
    int co  = blockIdx.x;
    int tid = threadIdx.x;
    float s = 0.f, q = 0.f;
    for (int i = tid; i < NBLK3; i += 256) {
        s += psum[i * 32 + co];
        q += psq[i * 32 + co];
    }
    __shared__ float ss[256], sq[256];
    ss[tid] = s; sq[tid] = q;
    __syncthreads();
    for (int st = 128; st > 0; st >>= 1) {
        if (tid < st) { ss[tid] += ss[tid + st]; sq[tid] += sq[tid + st]; }
        __syncthreads();
    }
    if (tid == 0) {
        const float N = 221184.f;  // 2*48^3
        float mean = ss[0] / N;
        float var  = sq[0] / N - mean * mean;
        float inv  = rsqrtf(var + 1e-5f);
        float A = gamma[co] * inv;
        stats[co * 2]     = A;
        stats[co * 2 + 1] = beta[co] - A * mean;
    }
}

// ---------------------------------------------------------------------------
// K5: y = A*o + B; out = y * sigmoid(y)   (float4 vectorized)
__global__ __launch_bounds__(256) void k_bn_silu(float* __restrict__ out,
                                                 const float* __restrict__ stats) {
    int idx4 = blockIdx.x * 256 + threadIdx.x;
    int co = (idx4 / (OUTN / 4)) & 31;
    float A = stats[co * 2], B = stats[co * 2 + 1];
    float4 o = ((const float4*)out)[idx4];
    float4 y;
    y.x = A * o.x + B; y.y = A * o.y + B; y.z = A * o.z + B; y.w = A * o.w + B;
    y.x = y.x / (1.f + __expf(-y.x));
    y.y = y.y / (1.f + __expf(-y.y));
    y.z = y.z / (1.f + __expf(-y.z));
    y.w = y.w / (1.f + __expf(-y.w));
    ((float4*)out)[idx4] = y;
}

// ---------------------------------------------------------------------------
extern "C" void kernel_launch(void* const* d_in, const int* in_sizes, int n_in,
                              void* d_out, int out_size, void* d_ws, size_t ws_size,
                              hipStream_t stream) {
    const float* x      = (const float*)d_in[0];
    const float* p_w    = (const float*)d_in[1];
    const float* p_b    = (const float*)d_in[2];
    const float* conv_w = (const float*)d_in[3];
    const float* gamma  = (const float*)d_in[4];
    const float* beta   = (const float*)d_in[5];
    float* out = (float*)d_out;
    float* ws  = (float*)d_ws;

    float* off   = ws;                       // 5,308,416 f
    float* xt    = off + 5308416;            // 1,048,576 f
    float* pwT   = xt + 1048576;             // 34,992 f
    float* psum  = pwT + 34992;              // 1728*32 = 55,296 f
    float* psq   = psum + 55296;             // 55,296 f
    float* stats = psq + 55296;              // 64 f
    ushort* wTb  = (ushort*)(stats + 64);    // 13,824 bf16 (= 6,912 f)
    ushort* xoffb = (ushort*)(stats + 64 + 6912);  // 28,311,552 bf16 (16B-aligned)

    k_wtrans<<<191, 256, 0, stream>>>(conv_w, p_w, wTb, pwT);
    k_xt<<<256, 256, 0, stream>>>(x, xt);
    k_offset_conv<<<768, 256, 0, stream>>>(x, pwT, p_b, off);
    k_interp<<<BATCH * BIGN / 256, 256, 0, stream>>>(xt, off, xoffb);
    k_conv2<<<NBLK3, 256, 0, stream>>>(xoffb, wTb, out, psum, psq);
    k_stats<<<32, 256, 0, stream>>>(psum, psq, gamma, beta, stats);
    k_bn_silu<<<NOUT / 1024, 256, 0, stream>>>(out, stats);
}

// Round 4
// 137.887 us; speedup vs baseline: 3.5866x; 1.5619x over previous
//
#include <hip/hip_runtime.h>
#include <hip/hip_bf16.h>

// Problem constants (fixed by setup_inputs)
constexpr int BATCH = 2;
constexpr int CIN   = 16;
constexpr int COUT  = 32;
constexpr int HWD   = 32768;        // 32^3
constexpr int OFFC  = 81;           // 3*27 offset channels
constexpr int BIG   = 96;           // 3*32
constexpr int BIG2  = BIG * BIG;    // 9216
constexpr int BIGN  = BIG * BIG * BIG;  // 884736
constexpr int OUTD  = 48;
constexpr int OUT2  = OUTD * OUTD;      // 2304
constexpr int OUTN  = OUTD * OUTD * OUTD; // 110592
constexpr int NOUT  = BATCH * COUT * OUTN; // 7077888
constexpr int NBLK3 = 1728;         // K3 grid: 2 bt x 24 ut x 6 vt x 6 wt

typedef __attribute__((ext_vector_type(8)))  short bf16x8;
typedef __attribute__((ext_vector_type(16))) float f32x16;

// ---------------------------------------------------------------------------
// K0a: weight transposes (both bf16, MFMA A-operand layout).
//  wTb [(tap*32+co)*16+ci] = bf16(conv_w[co][ci][tap])
//  pwTb[(tap*96+oc)*16+ci] = bf16(p_w[oc][ci][tap]), oc padded 81->96 w/ zeros
__global__ __launch_bounds__(256) void k_wtrans(const float* __restrict__ cw,
                                                const float* __restrict__ pw,
                                                ushort* __restrict__ wTb,
                                                ushort* __restrict__ pwTb) {
    int t = blockIdx.x * 256 + threadIdx.x;
    if (t < 13824) {
        int ci = t & 15; int rr = t >> 4; int co = rr & 31; int tap = rr >> 5;
        float v = cw[co * 432 + ci * 27 + tap];
        __hip_bfloat16 h = __float2bfloat16(v);
        wTb[t] = *(ushort*)&h;
    } else if (t < 13824 + 41472) {
        int u = t - 13824;
        int ci = u & 15; int rr = u >> 4; int oc = rr % 96; int tap = rr / 96;
        float v = (oc < 81) ? pw[oc * 432 + ci * 27 + tap] : 0.f;
        __hip_bfloat16 h = __float2bfloat16(v);
        pwTb[u] = *(ushort*)&h;
    }
}

// ---------------------------------------------------------------------------
// K0b: transpose x (b,ci,pos) -> xt fp32 (b,pos,ci) for K2 gathers, and
//      xb bf16 (b,pos,ci) for K1's MFMA staging.
__global__ __launch_bounds__(256) void k_xt(const float* __restrict__ x,
                                            float* __restrict__ xt,
                                            ushort* __restrict__ xb) {
    int t = blockIdx.x * 256 + threadIdx.x;   // 65536 threads
    int bt = t >> 15, pos = t & 32767;
    float v[16];
#pragma unroll
    for (int ci = 0; ci < 16; ci++) v[ci] = x[(bt * 16 + ci) * HWD + pos];
    float4* dst = (float4*)(xt + (size_t)t * 16);
    dst[0] = make_float4(v[0], v[1], v[2], v[3]);
    dst[1] = make_float4(v[4], v[5], v[6], v[7]);
    dst[2] = make_float4(v[8], v[9], v[10], v[11]);
    dst[3] = make_float4(v[12], v[13], v[14], v[15]);
    uint uw[8];
#pragma unroll
    for (int cc = 0; cc < 8; cc++) {
        __hip_bfloat16 h0 = __float2bfloat16(v[2 * cc]);
        __hip_bfloat16 h1 = __float2bfloat16(v[2 * cc + 1]);
        uw[cc] = (uint)(*(ushort*)&h0) | ((uint)(*(ushort*)&h1) << 16);
    }
    uint4* xd = (uint4*)(xb + (size_t)t * 16);
    xd[0] = make_uint4(uw[0], uw[1], uw[2], uw[3]);
    xd[1] = make_uint4(uw[4], uw[5], uw[6], uw[7]);
}

// ---------------------------------------------------------------------------
// K1: offset conv (stride 1, pad 1) as implicit-GEMM MFMA.
// Block = 2x8x8 positions, 4 waves; wave = 32-pos x 32-oc MFMA tile.
// 3 oc-groups (81 padded to 96) x 27 taps x mfma_f32_32x32x16_bf16 (K=16 ci).
// Halo 4x10x10 points x 16ci bf16 in LDS (W-pitch 11). Grid = 2 x 256 = 512.
__global__ __launch_bounds__(256) void k_offset_mfma(const ushort* __restrict__ xb,
                                                     const ushort* __restrict__ pwTb,
                                                     const float* __restrict__ p_b,
                                                     float* __restrict__ off) {
    __shared__ uint4 lds[4 * 10 * 11 * 2];   // 14,080 B
    int blk = blockIdx.x;
    int bt = blk >> 8; int r = blk & 255;
    int ut = r >> 4; int vt = (r >> 2) & 3; int wt = r & 3;
    int a0 = ut * 2, b0 = vt * 8, c0 = wt * 8;
    int tid = threadIdx.x;
    int wv = tid >> 6, l = tid & 63, col = l & 31, half = l >> 5;

    const ushort* xbb = xb + (size_t)bt * HWD * 16;
    for (int s = tid; s < 800; s += 256) {
        int h = s & 1, p = s >> 1;
        int su = p / 100; int rm = p - su * 100;
        int sv = rm / 10; int sw = rm - sv * 10;
        int ga = a0 - 1 + su, gb = b0 - 1 + sv, gc = c0 - 1 + sw;
        uint4 v = make_uint4(0, 0, 0, 0);
        if ((unsigned)ga < 32u && (unsigned)gb < 32u && (unsigned)gc < 32u)
            v = *(const uint4*)(xbb + (size_t)(ga * 1024 + gb * 32 + gc) * 16 + h * 8);
        lds[((su * 10 + sv) * 11 + sw) * 2 + h] = v;
    }
    __syncthreads();

    int U = wv >> 1, V = ((wv & 1) << 2) + (col >> 3), W = col & 7;
    const uint4* wt4 = (const uint4*)pwTb;
    int a = a0 + U, b = b0 + V, c = c0 + W;
    int pos = a * 1024 + b * 32 + c;
    float* ob = off + (size_t)bt * OFFC * HWD + pos;

#pragma unroll 1
    for (int g = 0; g < 3; g++) {
        bf16x8 wf[27];
#pragma unroll
        for (int t = 0; t < 27; t++)
            wf[t] = __builtin_bit_cast(bf16x8, wt4[(t * 96 + g * 32 + col) * 2 + half]);
        f32x16 acc;
#pragma unroll
        for (int i = 0; i < 16; i++) acc[i] = 0.f;
#pragma unroll
        for (int k1 = 0; k1 < 3; k1++)
#pragma unroll
        for (int k2 = 0; k2 < 3; k2++)
#pragma unroll
        for (int k3 = 0; k3 < 3; k3++) {
            bf16x8 xf = __builtin_bit_cast(bf16x8,
                lds[(((U + k1) * 10 + (V + k2)) * 11 + (W + k3)) * 2 + half]);
            acc = __builtin_amdgcn_mfma_f32_32x32x16_bf16(wf[(k1 * 3 + k2) * 3 + k3],
                                                          xf, acc, 0, 0, 0);
        }
#pragma unroll
        for (int rg = 0; rg < 16; rg++) {
            int co = g * 32 + (rg & 3) + 8 * (rg >> 2) + 4 * half;
            if (co < 81) ob[(size_t)co * HWD] = acc[rg] + p_b[co];
        }
    }
}

// ---------------------------------------------------------------------------
// K2: deformable 6-corner sampling -> x_off bf16 CHANNEL-LAST (bt, pos, 16ci)
__global__ __launch_bounds__(256) void k_interp(const float* __restrict__ xt,
                                                const float* __restrict__ off,
                                                ushort* __restrict__ xoffb) {
    int t  = blockIdx.x * 256 + threadIdx.x;
    int bt = t / BIGN;
    int bp = t - bt * BIGN;
    int A  = bp / BIG2;
    int r  = bp - A * BIG2;
    int Bc = r / BIG;
    int Cc = r - Bc * BIG;
    int a = A / 3,  i = A - a * 3;
    int b = Bc / 3, j = Bc - b * 3;
    int c = Cc / 3, k = Cc - c * 3;
    int n = i * 9 + j * 3 + k;
    int pos = a * 1024 + b * 32 + c;

    const float* ob = off + (size_t)bt * OFFC * HWD + pos;
    float ox = ob[(size_t)n * HWD];
    float oy = ob[(size_t)(27 + n) * HWD];
    float oz = ob[(size_t)(54 + n) * HWD];

    // reference quirk: px is based on the SECOND coord (b)+j, py on (a)+i
    float px = (float)(b + j) + ox;
    float py = (float)(a + i) + oy;
    float pz = (float)(c + k) + oz;

    float fx = floorf(px), fy = floorf(py), fz = floorf(pz);
    float ltx = fminf(fmaxf(fx, 0.f), 31.f);
    float lty = fminf(fmaxf(fy, 0.f), 31.f);
    float ltz = fminf(fmaxf(fz, 0.f), 31.f);
    float rbx = fminf(fmaxf(fx + 1.f, 0.f), 31.f);
    float rby = fminf(fmaxf(fy + 1.f, 0.f), 31.f);
    float rbz = fminf(fmaxf(fz + 1.f, 0.f), 31.f);
    float pcx = fminf(fmaxf(px, 0.f), 31.f);
    float pcy = fminf(fmaxf(py, 0.f), 31.f);
    float pcz = fminf(fmaxf(pz, 0.f), 31.f);

    float axl = 1.f + (ltx - pcx), axr = 1.f - (rbx - pcx);
    float ayl = 1.f + (lty - pcy), ayr = 1.f - (rby - pcy);
    float azl = 1.f + (ltz - pcz), azr = 1.f - (rbz - pcz);

    float g_lt = axl * ayl * azl;
    float g_rb = axr * ayr * azr;
    float g_lb = axl * ayr * azl;
    float g_rt = axr * ayl * azl;
    float g_lf = axl * ayl * azr;
    float g_rf = axr * ayr * azl;

    int iltx = (int)ltx, ilty = (int)lty, iltz = (int)ltz;
    int irbx = (int)rbx, irby = (int)rby, irbz = (int)rbz;

    int i_lt = iltx * 1024 + ilty * 32 + iltz;
    int i_rb = irbx * 1024 + irby * 32 + irbz;
    int i_lb = iltx * 1024 + irby * 32 + iltz;
    int i_rt = irbx * 1024 + ilty * 32 + iltz;
    int i_lf = iltx * 1024 + ilty * 32 + irbz;
    int i_rf = irbx * 1024 + irby * 32 + iltz;

    const float4* xb4 = (const float4*)(xt + (size_t)bt * HWD * 16);
    float4 a0 = make_float4(0.f, 0.f, 0.f, 0.f), a1 = a0, a2 = a0, a3 = a0;

    auto corner = [&](float g, int ip) {
        const float4* p = xb4 + (size_t)ip * 4;
        float4 v0 = p[0], v1 = p[1], v2 = p[2], v3 = p[3];
        a0.x += g * v0.x; a0.y += g * v0.y; a0.z += g * v0.z; a0.w += g * v0.w;
        a1.x += g * v1.x; a1.y += g * v1.y; a1.z += g * v1.z; a1.w += g * v1.w;
        a2.x += g * v2.x; a2.y += g * v2.y; a2.z += g * v2.z; a2.w += g * v2.w;
        a3.x += g * v3.x; a3.y += g * v3.y; a3.z += g * v3.z; a3.w += g * v3.w;
    };
    corner(g_lt, i_lt);
    corner(g_rb, i_rb);
    corner(g_lb, i_lb);
    corner(g_rt, i_rt);
    corner(g_lf, i_lf);
    corner(g_rf, i_rf);

    float vals[16] = {a0.x, a0.y, a0.z, a0.w, a1.x, a1.y, a1.z, a1.w,
                      a2.x, a2.y, a2.z, a2.w, a3.x, a3.y, a3.z, a3.w};
    uint uw[8];
#pragma unroll
    for (int cc = 0; cc < 8; cc++) {
        __hip_bfloat16 h0 = __float2bfloat16(vals[2 * cc]);
        __hip_bfloat16 h1 = __float2bfloat16(vals[2 * cc + 1]);
        uw[cc] = (uint)(*(ushort*)&h0) | ((uint)(*(ushort*)&h1) << 16);
    }
    uint4* dst = (uint4*)(xoffb + (size_t)(bt * (size_t)BIGN + bp) * 16);
    dst[0] = make_uint4(uw[0], uw[1], uw[2], uw[3]);
    dst[1] = make_uint4(uw[4], uw[5], uw[6], uw[7]);
}

// ---------------------------------------------------------------------------
// K3: conv3d(x_off, conv_w, stride=2, pad=1) as implicit-GEMM MFMA.
// Block = 2x8x8 output tile, 4 waves; wave = one 32-position x 32-co MFMA tile.
// 27 taps x mfma_f32_32x32x16_bf16 (K=16 ci). A = weights [co][ci] (row=co),
// B = x [ci][pos] (col=pos)  ->  D[co][pos], position-major stores.
// LDS halo: [su 0..4][sv 0..16][W-slot even/odd split, pad 19][16 ci] bf16.
__global__ __launch_bounds__(256, 3) void k_conv2(const ushort* __restrict__ xoffb,
                                                  const ushort* __restrict__ wTb,
                                                  float* __restrict__ out,
                                                  float* __restrict__ psum,
                                                  float* __restrict__ psq) {
    __shared__ uint4 lds[5 * 17 * 19 * 2];   // 51,680 B
    __shared__ float ls[4][32], lq[4][32];

    int blk = blockIdx.x;
    int bt = blk / 864; int r = blk - bt * 864;
    int ut = r / 36; r -= ut * 36;
    int vt = r / 6;  int wt = r - vt * 6;

    int tid = threadIdx.x;
    int wv = tid >> 6, l = tid & 63;
    int col = l & 31, half = l >> 5;

    // preload all 27 weight fragments (A operand): w[co=col][ci=half*8..+7]
    bf16x8 wf[27];
    const uint4* wt4 = (const uint4*)wTb;
#pragma unroll
    for (int t = 0; t < 27; t++)
        wf[t] = __builtin_bit_cast(bf16x8, wt4[(t * 32 + col) * 2 + half]);

    // stage halo (5 x 17 x 17 points x 16ci bf16), even/odd W split, row pad 19
    const ushort* xb = xoffb + (size_t)bt * BIGN * 16;
    int gU0 = ut * 4 - 1, gV0 = vt * 16 - 1, gW0 = wt * 16 - 1;
    for (int s = tid; s < 2890; s += 256) {
        int h = s & 1, p = s >> 1;
        int su = p / 289; int rm = p - su * 289;
        int sv = rm / 17; int sw = rm - sv * 17;
        int gU = gU0 + su, gV = gV0 + sv, gW = gW0 + sw;
        uint4 v = make_uint4(0, 0, 0, 0);
        if ((unsigned)gU < 96u && (unsigned)gV < 96u && (unsigned)gW < 96u)
            v = *(const uint4*)(xb + (size_t)(gU * 9216 + gV * 96 + gW) * 16 + h * 8);
        int slot = (sw & 1) * 9 + (sw >> 1);
        lds[((su * 17 + sv) * 19 + slot) * 2 + h] = v;
    }
    __syncthreads();

    // wave tile: U = wv>>1 in {0,1}; V = (wv&1)*4 + col>>3; W = col&7
    int U = wv >> 1, V = (wv & 1) * 4 + (col >> 3), W = col & 7;
    const uint4* lp = &lds[(((2 * U * 17 + 2 * V) * 19) + W) * 2 + half];

    f32x16 acc;
#pragma unroll
    for (int i = 0; i < 16; i++) acc[i] = 0.f;

#pragma unroll
    for (int k1 = 0; k1 < 3; k1++)
#pragma unroll
    for (int k2 = 0; k2 < 3; k2++)
#pragma unroll
    for (int k3 = 0; k3 < 3; k3++) {
        // sw = 2W + k3 -> slot offset {0, 9, 1}
        const int so = (k3 == 0) ? 0 : (k3 == 1 ? 9 : 1);
        const int off = ((k1 * 17 + k2) * 19 + so) * 2;
        bf16x8 xf = __builtin_bit_cast(bf16x8, lp[off]);
        acc = __builtin_amdgcn_mfma_f32_32x32x16_bf16(wf[(k1 * 3 + k2) * 3 + k3],
                                                      xf, acc, 0, 0, 0);
    }

    // store: D row = co = (rg&3)+8*(rg>>2)+4*half, col = position
    int u = ut * 2 + U, v = vt * 8 + V, wg = wt * 8 + W;
    size_t posg = (size_t)u * OUT2 + v * OUTD + wg;
    float* ob = out + (size_t)bt * COUT * OUTN;
#pragma unroll
    for (int rg = 0; rg < 16; rg++) {
        int co = (rg & 3) + 8 * (rg >> 2) + 4 * half;
        ob[(size_t)co * OUTN + posg] = acc[rg];
    }

    // fixed-order block stats (sum over the 32 positions per half-wave)
#pragma unroll
    for (int rg = 0; rg < 16; rg++) {
        float s = acc[rg], q = acc[rg] * acc[rg];
#pragma unroll
        for (int o = 1; o < 32; o <<= 1) {
            s += __shfl_xor(s, o);
            q += __shfl_xor(q, o);
        }
        if (col == 0) {
            int co = (rg & 3) + 8 * (rg >> 2) + 4 * half;
            ls[wv][co] = s; lq[wv][co] = q;
        }
    }
    __syncthreads();
    if (tid < 32) {
        float s = ls[0][tid] + ls[1][tid] + ls[2][tid] + ls[3][tid];
        float q = lq[0][tid] + lq[1][tid] + lq[2][tid] + lq[3][tid];
        psum[blk * 32 + tid] = s;
        psq[blk * 32 + tid]  = q;
    }
}

// ---------------------------------------------------------------------------
// K4: reduce partials -> per-channel scale A and shift B
__global__ __launch_bounds__(256) void k_stats(const float* __restrict__ psum,
                                               const float* __restrict__ psq,
                                               const float* __restrict__ gamma,
                                               const float* __restrict__ beta,
                                               float* __restrict__ stats) {
    int co  = blockIdx.x;
    int tid = threadIdx.x;
    float s = 0.f, q = 0.f;
    for (int i = tid; i < NBLK3; i += 256) {
        s += psum[i * 32 + co];
        q += psq[i * 32 + co];
    }
    __shared__ float ss[256], sq[256];
    ss[tid] = s; sq[tid] = q;
    __syncthreads();
    for (int st = 128; st > 0; st >>= 1) {
        if (tid < st) { ss[tid] += ss[tid + st]; sq[tid] += sq[tid + st]; }
        __syncthreads();
    }
    if (tid == 0) {
        const float N = 221184.f;  // 2*48^3
        float mean = ss[0] / N;
        float var  = sq[0] / N - mean * mean;
        float inv  = rsqrtf(var + 1e-5f);
        float A = gamma[co] * inv;
        stats[co * 2]     = A;
        stats[co * 2 + 1] = beta[co] - A * mean;
    }
}

// ---------------------------------------------------------------------------
// K5: y = A*o + B; out = y * sigmoid(y)   (float4 vectorized)
__global__ __launch_bounds__(256) void k_bn_silu(float* __restrict__ out,
                                                 const float* __restrict__ stats) {
    int idx4 = blockIdx.x * 256 + threadIdx.x;
    int co = (idx4 / (OUTN / 4)) & 31;
    float A = stats[co * 2], B = stats[co * 2 + 1];
    float4 o = ((const float4*)out)[idx4];
    float4 y;
    y.x = A * o.x + B; y.y = A * o.y + B; y.z = A * o.z + B; y.w = A * o.w + B;
    y.x = y.x / (1.f + __expf(-y.x));
    y.y = y.y / (1.f + __expf(-y.y));
    y.z = y.z / (1.f + __expf(-y.z));
    y.w = y.w / (1.f + __expf(-y.w));
    ((float4*)out)[idx4] = y;
}

// ---------------------------------------------------------------------------
extern "C" void kernel_launch(void* const* d_in, const int* in_sizes, int n_in,
                              void* d_out, int out_size, void* d_ws, size_t ws_size,
                              hipStream_t stream) {
    const float* x      = (const float*)d_in[0];
    const float* p_w    = (const float*)d_in[1];
    const float* p_b    = (const float*)d_in[2];
    const float* conv_w = (const float*)d_in[3];
    const float* gamma  = (const float*)d_in[4];
    const float* beta   = (const float*)d_in[5];
    float* out = (float*)d_out;
    float* ws  = (float*)d_ws;

    float* off   = ws;                       // 5,308,416 f
    float* xt    = off + 5308416;            // 1,048,576 f
    float* psum  = xt + 1048576;             // 1728*32 = 55,296 f
    float* psq   = psum + 55296;             // 55,296 f
    float* stats = psq + 55296;              // 64 f
    ushort* wTb  = (ushort*)(stats + 64);    // 13,824 bf16 = 6,912 f
    ushort* pwTb = wTb + 13824;              // 41,472 bf16 = 20,736 f
    ushort* xb   = pwTb + 41472;             // 1,048,576 bf16 = 524,288 f
    ushort* xoffb = xb + 1048576;            // 28,311,552 bf16 (16B-aligned)

    k_wtrans<<<216, 256, 0, stream>>>(conv_w, p_w, wTb, pwTb);
    k_xt<<<256, 256, 0, stream>>>(x, xt, xb);
    k_offset_mfma<<<512, 256, 0, stream>>>(xb, pwTb, p_b, off);
    k_interp<<<BATCH * BIGN / 256, 256, 0, stream>>>(xt, off, xoffb);
    k_conv2<<<NBLK3, 256, 0, stream>>>(xoffb, wTb, out, psum, psq);
    k_stats<<<32, 256, 0, stream>>>(psum, psq, gamma, beta, stats);
    k_bn_silu<<<NOUT / 1024, 256, 0, stream>>>(out, stats);
}

// Round 5
// 101.812 us; speedup vs baseline: 4.8574x; 1.3543x over previous
//
#include <hip/hip_runtime.h>
#include <hip/hip_bf16.h>

// Problem constants (fixed by setup_inputs)
constexpr int BATCH = 2;
constexpr int CIN   = 16;
constexpr int COUT  = 32;
constexpr int HWD   = 32768;        // 32^3
constexpr int OFFC  = 81;           // 3*27 offset channels
constexpr int BIG   = 96;           // 3*32
constexpr int BIG2  = BIG * BIG;    // 9216
constexpr int BIGN  = BIG * BIG * BIG;  // 884736
constexpr int OUTD  = 48;
constexpr int OUT2  = OUTD * OUTD;      // 2304
constexpr int OUTN  = OUTD * OUTD * OUTD; // 110592
constexpr int NOUT  = BATCH * COUT * OUTN; // 7077888
constexpr int NBLK3 = 1728;         // fused grid: 2 bt x 24 ut x 6 vt x 6 wt

typedef __attribute__((ext_vector_type(8)))  short bf16x8;
typedef __attribute__((ext_vector_type(16))) float f32x16;

__device__ __forceinline__ float bf_lo(uint u) { return __uint_as_float(u << 16); }
__device__ __forceinline__ float bf_hi(uint u) { return __uint_as_float(u & 0xFFFF0000u); }

// ---------------------------------------------------------------------------
// K0a: weight transposes (both bf16, MFMA A-operand layout).
//  wTb [(tap*32+co)*16+ci] = bf16(conv_w[co][ci][tap])
//  pwTb[(tap*96+oc)*16+ci] = bf16(p_w[oc][ci][tap]), oc padded 81->96 w/ zeros
__global__ __launch_bounds__(256) void k_wtrans(const float* __restrict__ cw,
                                                const float* __restrict__ pw,
                                                ushort* __restrict__ wTb,
                                                ushort* __restrict__ pwTb) {
    int t = blockIdx.x * 256 + threadIdx.x;
    if (t < 13824) {
        int ci = t & 15; int rr = t >> 4; int co = rr & 31; int tap = rr >> 5;
        float v = cw[co * 432 + ci * 27 + tap];
        __hip_bfloat16 h = __float2bfloat16(v);
        wTb[t] = *(ushort*)&h;
    } else if (t < 13824 + 41472) {
        int u = t - 13824;
        int ci = u & 15; int rr = u >> 4; int oc = rr % 96; int tap = rr / 96;
        float v = (oc < 81) ? pw[oc * 432 + ci * 27 + tap] : 0.f;
        __hip_bfloat16 h = __float2bfloat16(v);
        pwTb[u] = *(ushort*)&h;
    }
}

// ---------------------------------------------------------------------------
// K0b: transpose x (b,ci,pos) -> xb bf16 channel-last (b,pos,16ci)
__global__ __launch_bounds__(256) void k_xt(const float* __restrict__ x,
                                            ushort* __restrict__ xb) {
    int t = blockIdx.x * 256 + threadIdx.x;   // 65536 threads
    int bt = t >> 15, pos = t & 32767;
    float v[16];
#pragma unroll
    for (int ci = 0; ci < 16; ci++) v[ci] = x[(bt * 16 + ci) * HWD + pos];
    uint uw[8];
#pragma unroll
    for (int cc = 0; cc < 8; cc++) {
        __hip_bfloat16 h0 = __float2bfloat16(v[2 * cc]);
        __hip_bfloat16 h1 = __float2bfloat16(v[2 * cc + 1]);
        uw[cc] = (uint)(*(ushort*)&h0) | ((uint)(*(ushort*)&h1) << 16);
    }
    uint4* xd = (uint4*)(xb + (size_t)t * 16);
    xd[0] = make_uint4(uw[0], uw[1], uw[2], uw[3]);
    xd[1] = make_uint4(uw[4], uw[5], uw[6], uw[7]);
}

// ---------------------------------------------------------------------------
// K1: offset conv (stride 1, pad 1) as implicit-GEMM MFMA.
// Block = 2x8x8 positions, 4 waves; wave = 32-pos x 32-oc MFMA tile.
// 3 oc-groups (81 padded to 96) x 27 taps x mfma_f32_32x32x16_bf16 (K=16 ci).
__global__ __launch_bounds__(256) void k_offset_mfma(const ushort* __restrict__ xb,
                                                     const ushort* __restrict__ pwTb,
                                                     const float* __restrict__ p_b,
                                                     float* __restrict__ off) {
    __shared__ uint4 lds[4 * 10 * 11 * 2];   // 14,080 B
    int blk = blockIdx.x;
    int bt = blk >> 8; int r = blk & 255;
    int ut = r >> 4; int vt = (r >> 2) & 3; int wt = r & 3;
    int a0 = ut * 2, b0 = vt * 8, c0 = wt * 8;
    int tid = threadIdx.x;
    int wv = tid >> 6, l = tid & 63, col = l & 31, half = l >> 5;

    const ushort* xbb = xb + (size_t)bt * HWD * 16;
    for (int s = tid; s < 800; s += 256) {
        int h = s & 1, p = s >> 1;
        int su = p / 100; int rm = p - su * 100;
        int sv = rm / 10; int sw = rm - sv * 10;
        int ga = a0 - 1 + su, gb = b0 - 1 + sv, gc = c0 - 1 + sw;
        uint4 v = make_uint4(0, 0, 0, 0);
        if ((unsigned)ga < 32u && (unsigned)gb < 32u && (unsigned)gc < 32u)
            v = *(const uint4*)(xbb + (size_t)(ga * 1024 + gb * 32 + gc) * 16 + h * 8);
        lds[((su * 10 + sv) * 11 + sw) * 2 + h] = v;
    }
    __syncthreads();

    int U = wv >> 1, V = ((wv & 1) << 2) + (col >> 3), W = col & 7;
    const uint4* wt4 = (const uint4*)pwTb;
    int a = a0 + U, b = b0 + V, c = c0 + W;
    int pos = a * 1024 + b * 32 + c;
    float* ob = off + (size_t)bt * OFFC * HWD + pos;

#pragma unroll 1
    for (int g = 0; g < 3; g++) {
        bf16x8 wf[27];
#pragma unroll
        for (int t = 0; t < 27; t++)
            wf[t] = __builtin_bit_cast(bf16x8, wt4[(t * 96 + g * 32 + col) * 2 + half]);
        f32x16 acc;
#pragma unroll
        for (int i = 0; i < 16; i++) acc[i] = 0.f;
#pragma unroll
        for (int k1 = 0; k1 < 3; k1++)
#pragma unroll
        for (int k2 = 0; k2 < 3; k2++)
#pragma unroll
        for (int k3 = 0; k3 < 3; k3++) {
            bf16x8 xf = __builtin_bit_cast(bf16x8,
                lds[(((U + k1) * 10 + (V + k2)) * 11 + (W + k3)) * 2 + half]);
            acc = __builtin_amdgcn_mfma_f32_32x32x16_bf16(wf[(k1 * 3 + k2) * 3 + k3],
                                                          xf, acc, 0, 0, 0);
        }
#pragma unroll
        for (int rg = 0; rg < 16; rg++) {
            int co = g * 32 + (rg & 3) + 8 * (rg >> 2) + 4 * half;
            if (co < 81) ob[(size_t)co * HWD] = acc[rg] + p_b[co];
        }
    }
}

// ---------------------------------------------------------------------------
// K2+K3 fused: deformable sampling computed DIRECTLY into the conv's LDS halo
// (x_off never materialized), then conv3d(.,stride=2,pad=1) as MFMA GEMM.
// Block = 2x8x8 output tile, 4 waves; wave = 32-pos x 32-co MFMA tile.
// LDS halo: [su 0..4][sv 0..16][W even/odd slots, pitch 19][16 ci] bf16.
__global__ __launch_bounds__(256, 3) void k_fused(const ushort* __restrict__ xb,
                                                  const float* __restrict__ off,
                                                  const ushort* __restrict__ wTb,
                                                  ushort* __restrict__ o16,
                                                  float* __restrict__ psum,
                                                  float* __restrict__ psq) {
    __shared__ uint4 lds[5 * 17 * 19 * 2];   // 51,680 B
    __shared__ float ls[4][32], lq[4][32];

    int blk = blockIdx.x;
    int bt = blk / 864; int r = blk - bt * 864;
    int ut = r / 36; r -= ut * 36;
    int vt = r / 6;  int wt = r - vt * 6;

    int tid = threadIdx.x;
    int wv = tid >> 6, l = tid & 63;
    int col = l & 31, half = l >> 5;

    // ---- staging phase: interpolate halo points straight into LDS ----
    const ushort* xbb = xb + (size_t)bt * HWD * 16;
    const float* offb = off + (size_t)bt * OFFC * HWD;
    int gU0 = ut * 4 - 1, gV0 = vt * 16 - 1, gW0 = wt * 16 - 1;

    for (int s = tid; s < 1445; s += 256) {
        int su = s / 289; int rm = s - su * 289;
        int sv = rm / 17; int sw = rm - sv * 17;
        int gU = gU0 + su, gV = gV0 + sv, gW = gW0 + sw;
        uint4 r0 = make_uint4(0, 0, 0, 0), r1 = r0;
        if ((unsigned)gU < 96u && (unsigned)gV < 96u && (unsigned)gW < 96u) {
            int a = gU / 3, i = gU - a * 3;
            int b = gV / 3, j = gV - b * 3;
            int c = gW / 3, kk = gW - c * 3;
            int n = i * 9 + j * 3 + kk;
            int pos = a * 1024 + b * 32 + c;
            float ox = offb[(size_t)n * HWD + pos];
            float oy = offb[(size_t)(27 + n) * HWD + pos];
            float oz = offb[(size_t)(54 + n) * HWD + pos];

            // reference quirk: px is based on the SECOND coord (b)+j, py on (a)+i
            float px = (float)(b + j) + ox;
            float py = (float)(a + i) + oy;
            float pz = (float)(c + kk) + oz;

            float fx = floorf(px), fy = floorf(py), fz = floorf(pz);
            float ltx = fminf(fmaxf(fx, 0.f), 31.f);
            float lty = fminf(fmaxf(fy, 0.f), 31.f);
            float ltz = fminf(fmaxf(fz, 0.f), 31.f);
            float rbx = fminf(fmaxf(fx + 1.f, 0.f), 31.f);
            float rby = fminf(fmaxf(fy + 1.f, 0.f), 31.f);
            float rbz = fminf(fmaxf(fz + 1.f, 0.f), 31.f);
            float pcx = fminf(fmaxf(px, 0.f), 31.f);
            float pcy = fminf(fmaxf(py, 0.f), 31.f);
            float pcz = fminf(fmaxf(pz, 0.f), 31.f);

            float axl = 1.f + (ltx - pcx), axr = 1.f - (rbx - pcx);
            float ayl = 1.f + (lty - pcy), ayr = 1.f - (rby - pcy);
            float azl = 1.f + (ltz - pcz), azr = 1.f - (rbz - pcz);

            float g_lt = axl * ayl * azl;
            float g_rb = axr * ayr * azr;
            float g_lb = axl * ayr * azl;
            float g_rt = axr * ayl * azl;
            float g_lf = axl * ayl * azr;
            float g_rf = axr * ayr * azl;

            int iltx = (int)ltx, ilty = (int)lty, iltz = (int)ltz;
            int irbx = (int)rbx, irby = (int)rby, irbz = (int)rbz;

            int i_lt = iltx * 1024 + ilty * 32 + iltz;
            int i_rb = irbx * 1024 + irby * 32 + irbz;
            int i_lb = iltx * 1024 + irby * 32 + iltz;
            int i_rt = irbx * 1024 + ilty * 32 + iltz;
            int i_lf = iltx * 1024 + ilty * 32 + irbz;
            int i_rf = irbx * 1024 + irby * 32 + iltz;

            float acc[16];
#pragma unroll
            for (int q = 0; q < 16; q++) acc[q] = 0.f;

            auto corner = [&](float g, int ip) {
                const uint4* p = (const uint4*)(xbb + (size_t)ip * 16);
                uint4 u0 = p[0], u1 = p[1];
                acc[0]  += g * bf_lo(u0.x); acc[1]  += g * bf_hi(u0.x);
                acc[2]  += g * bf_lo(u0.y); acc[3]  += g * bf_hi(u0.y);
                acc[4]  += g * bf_lo(u0.z); acc[5]  += g * bf_hi(u0.z);
                acc[6]  += g * bf_lo(u0.w); acc[7]  += g * bf_hi(u0.w);
                acc[8]  += g * bf_lo(u1.x); acc[9]  += g * bf_hi(u1.x);
                acc[10] += g * bf_lo(u1.y); acc[11] += g * bf_hi(u1.y);
                acc[12] += g * bf_lo(u1.z); acc[13] += g * bf_hi(u1.z);
                acc[14] += g * bf_lo(u1.w); acc[15] += g * bf_hi(u1.w);
            };
            corner(g_lt, i_lt);
            corner(g_rb, i_rb);
            corner(g_lb, i_lb);
            corner(g_rt, i_rt);
            corner(g_lf, i_lf);
            corner(g_rf, i_rf);

            uint uw[8];
#pragma unroll
            for (int cc = 0; cc < 8; cc++) {
                __hip_bfloat16 h0 = __float2bfloat16(acc[2 * cc]);
                __hip_bfloat16 h1 = __float2bfloat16(acc[2 * cc + 1]);
                uw[cc] = (uint)(*(ushort*)&h0) | ((uint)(*(ushort*)&h1) << 16);
            }
            r0 = make_uint4(uw[0], uw[1], uw[2], uw[3]);
            r1 = make_uint4(uw[4], uw[5], uw[6], uw[7]);
        }
        int slot = (sw & 1) * 9 + (sw >> 1);   // even/odd W split
        lds[((su * 17 + sv) * 19 + slot) * 2 + 0] = r0;
        lds[((su * 17 + sv) * 19 + slot) * 2 + 1] = r1;
    }

    // preload 27 weight fragments (A operand): w[co=col][ci=half*8..+7]
    bf16x8 wf[27];
    const uint4* wt4 = (const uint4*)wTb;
#pragma unroll
    for (int t = 0; t < 27; t++)
        wf[t] = __builtin_bit_cast(bf16x8, wt4[(t * 32 + col) * 2 + half]);

    __syncthreads();

    // ---- MFMA phase ----
    int U = wv >> 1, V = (wv & 1) * 4 + (col >> 3), W = col & 7;
    const uint4* lp = &lds[(((2 * U * 17 + 2 * V) * 19) + W) * 2 + half];

    f32x16 acc;
#pragma unroll
    for (int i = 0; i < 16; i++) acc[i] = 0.f;

#pragma unroll
    for (int k1 = 0; k1 < 3; k1++)
#pragma unroll
    for (int k2 = 0; k2 < 3; k2++)
#pragma unroll
    for (int k3 = 0; k3 < 3; k3++) {
        // sw = 2W + k3 -> slot offset {0, 9, 1}
        const int so = (k3 == 0) ? 0 : (k3 == 1 ? 9 : 1);
        const int off2 = ((k1 * 17 + k2) * 19 + so) * 2;
        bf16x8 xf = __builtin_bit_cast(bf16x8, lp[off2]);
        acc = __builtin_amdgcn_mfma_f32_32x32x16_bf16(wf[(k1 * 3 + k2) * 3 + k3],
                                                      xf, acc, 0, 0, 0);
    }

    // store bf16: D row = co = (rg&3)+8*(rg>>2)+4*half, col = position
    int u = ut * 2 + U, v = vt * 8 + V, wg = wt * 8 + W;
    size_t posg = (size_t)u * OUT2 + v * OUTD + wg;
    ushort* ob = o16 + (size_t)bt * COUT * OUTN;
#pragma unroll
    for (int rg = 0; rg < 16; rg++) {
        int co = (rg & 3) + 8 * (rg >> 2) + 4 * half;
        __hip_bfloat16 h = __float2bfloat16(acc[rg]);
        ob[(size_t)co * OUTN + posg] = *(ushort*)&h;
    }

    // fixed-order block stats (fp32, from exact accumulators)
#pragma unroll
    for (int rg = 0; rg < 16; rg++) {
        float s = acc[rg], q = acc[rg] * acc[rg];
#pragma unroll
        for (int o = 1; o < 32; o <<= 1) {
            s += __shfl_xor(s, o);
            q += __shfl_xor(q, o);
        }
        if (col == 0) {
            int co = (rg & 3) + 8 * (rg >> 2) + 4 * half;
            ls[wv][co] = s; lq[wv][co] = q;
        }
    }
    __syncthreads();
    if (tid < 32) {
        float s = ls[0][tid] + ls[1][tid] + ls[2][tid] + ls[3][tid];
        float q = lq[0][tid] + lq[1][tid] + lq[2][tid] + lq[3][tid];
        psum[blk * 32 + tid] = s;
        psq[blk * 32 + tid]  = q;
    }
}

// ---------------------------------------------------------------------------
// K4: reduce partials -> per-channel scale A and shift B
__global__ __launch_bounds__(256) void k_stats(const float* __restrict__ psum,
                                               const float* __restrict__ psq,
                                               const float* __restrict__ gamma,
                                               const float* __restrict__ beta,
                                               float* __restrict__ stats) {
    int co  = blockIdx.x;
    int tid = threadIdx.x;
    float s = 0.f, q = 0.f;
    for (int i = tid; i < NBLK3; i += 256) {
        s += psum[i * 32 + co];
        q += psq[i * 32 + co];
    }
    __shared__ float ss[256], sq[256];
    ss[tid] = s; sq[tid] = q;
    __syncthreads();
    for (int st = 128; st > 0; st >>= 1) {
        if (tid < st) { ss[tid] += ss[tid + st]; sq[tid] += sq[tid + st]; }
        __syncthreads();
    }
    if (tid == 0) {
        const float N = 221184.f;  // 2*48^3
        float mean = ss[0] / N;
        float var  = sq[0] / N - mean * mean;
        float inv  = rsqrtf(var + 1e-5f);
        float A = gamma[co] * inv;
        stats[co * 2]     = A;
        stats[co * 2 + 1] = beta[co] - A * mean;
    }
}

// ---------------------------------------------------------------------------
// K5: y = A*bf16(o) + B; out = y * sigmoid(y)  (8 values/thread)
__global__ __launch_bounds__(256) void k_bn_silu(const ushort* __restrict__ o16,
                                                 const float* __restrict__ stats,
                                                 float* __restrict__ out) {
    int t = blockIdx.x * 256 + threadIdx.x;       // NOUT/8 threads
    int co = (t / (OUTN / 8)) & 31;
    float A = stats[co * 2], B = stats[co * 2 + 1];
    uint4 u = ((const uint4*)o16)[t];
    float o[8] = {bf_lo(u.x), bf_hi(u.x), bf_lo(u.y), bf_hi(u.y),
                  bf_lo(u.z), bf_hi(u.z), bf_lo(u.w), bf_hi(u.w)};
    float y[8];
#pragma unroll
    for (int q = 0; q < 8; q++) {
        float yy = A * o[q] + B;
        y[q] = yy / (1.f + __expf(-yy));
    }
    float4* dst = (float4*)(out + (size_t)t * 8);
    dst[0] = make_float4(y[0], y[1], y[2], y[3]);
    dst[1] = make_float4(y[4], y[5], y[6], y[7]);
}

// ---------------------------------------------------------------------------
extern "C" void kernel_launch(void* const* d_in, const int* in_sizes, int n_in,
                              void* d_out, int out_size, void* d_ws, size_t ws_size,
                              hipStream_t stream) {
    const float* x      = (const float*)d_in[0];
    const float* p_w    = (const float*)d_in[1];
    const float* p_b    = (const float*)d_in[2];
    const float* conv_w = (const float*)d_in[3];
    const float* gamma  = (const float*)d_in[4];
    const float* beta   = (const float*)d_in[5];
    float* out = (float*)d_out;
    float* ws  = (float*)d_ws;

    float* off   = ws;                       // 5,308,416 f
    float* psum  = off + 5308416;            // 1728*32 = 55,296 f
    float* psq   = psum + 55296;             // 55,296 f
    float* stats = psq + 55296;              // 64 f
    ushort* wTb  = (ushort*)(stats + 64);    // 13,824 bf16
    ushort* pwTb = wTb + 13824;              // 41,472 bf16
    ushort* xb   = pwTb + 41472;             // 1,048,576 bf16
    ushort* o16  = xb + 1048576;             // 7,077,888 bf16

    k_wtrans<<<216, 256, 0, stream>>>(conv_w, p_w, wTb, pwTb);
    k_xt<<<256, 256, 0, stream>>>(x, xb);
    k_offset_mfma<<<512, 256, 0, stream>>>(xb, pwTb, p_b, off);
    k_fused<<<NBLK3, 256, 0, stream>>>(xb, off, wTb, o16, psum, psq);
    k_stats<<<32, 256, 0, stream>>>(psum, psq, gamma, beta, stats);
    k_bn_silu<<<NOUT / 2048, 256, 0, stream>>>(o16, stats, out);
}